// Round 1
// baseline (227.499 us; speedup 1.0000x reference)
//
#include <hip/hip_runtime.h>
#include <math.h>

// LocalContrastNormalization: out = sigmoid(0.5 * (x - mu) / (sigma + eps))
// mu, sigma from a 31x31 zero-padded box filter (separable).
// Fully fused single kernel: vertical box via per-thread register sliding
// window over rows; horizontal box via LDS row of (sum, sumsq) with zero pads.

#define KSZ   31
#define PAD   15
#define IMG_H 1024
#define IMG_W 1024
#define SH    64          // output rows per block
#define EPSV  1e-5f

__global__ __launch_bounds__(256)
void lcn_fused_kernel(const float* __restrict__ x, float* __restrict__ out) {
    const int t     = threadIdx.x;
    const int chunk = blockIdx.x & ((IMG_H / SH) - 1);   // 16 chunks per image
    const int b     = blockIdx.x / (IMG_H / SH);
    const int y0    = chunk * SH;

    const float* img  = x   + (size_t)b * IMG_H * IMG_W;
    float*       oimg = out + (size_t)b * IMG_H * IMG_W;

    // LDS: one row of vertical (sum, sumsq) with 16-element zero pad each side.
    __shared__ float2 vrow[IMG_W + 32];   // 1056 * 8B = 8448 B

    if (t < 16) {
        vrow[t]              = make_float2(0.f, 0.f);
        vrow[IMG_W + 16 + t] = make_float2(0.f, 0.f);
    }

    // Vertical running sums for columns c_j = t + 256*j  (j = 0..3)
    float vs0 = 0.f, vq0 = 0.f, vs1 = 0.f, vq1 = 0.f;
    float vs2 = 0.f, vq2 = 0.f, vs3 = 0.f, vq3 = 0.f;

    // Warm-up: accumulate rows [y0-15, y0+15] clipped to [0, H)
    for (int y = y0 - PAD; y <= y0 + PAD; ++y) {
        if (y < 0 || y >= IMG_H) continue;
        const float* row = img + (size_t)y * IMG_W;
        float v0 = row[t];
        float v1 = row[t + 256];
        float v2 = row[t + 512];
        float v3 = row[t + 768];
        vs0 += v0; vq0 += v0 * v0;
        vs1 += v1; vq1 += v1 * v1;
        vs2 += v2; vq2 += v2 * v2;
        vs3 += v3; vq3 += v3 * v3;
    }

    const float inv = 1.0f / (float)(KSZ * KSZ);

    for (int yo = y0; yo < y0 + SH; ++yo) {
        // Publish vertical sums for this output row.
        vrow[16 + t      ] = make_float2(vs0, vq0);
        vrow[16 + t + 256] = make_float2(vs1, vq1);
        vrow[16 + t + 512] = make_float2(vs2, vq2);
        vrow[16 + t + 768] = make_float2(vs3, vq3);
        __syncthreads();

        const float* xrow = img  + (size_t)yo * IMG_W;
        float*       orow = oimg + (size_t)yo * IMG_W;

        #pragma unroll
        for (int u = 0; u < 4; ++u) {
            const int o = t + 256 * u;
            float hs = 0.f, hq = 0.f;
            #pragma unroll
            for (int k = 0; k < KSZ; ++k) {
                // window cols [o-15, o+15]; +16 pad offset -> index o+1+k
                float2 v = vrow[o + 1 + k];
                hs += v.x;
                hq += v.y;
            }
            const float mean = hs * inv;
            const float sqm  = hq * inv;
            const float var  = sqm - mean * mean;
            const float stdv = sqrtf(fmaxf(var, EPSV));
            const float xc   = xrow[o];
            const float norm = (xc - mean) / (stdv + EPSV);
            orow[o] = 1.0f / (1.0f + expf(-0.5f * norm));
        }
        __syncthreads();   // vrow rewritten next iteration

        // Slide vertical window: drop row yo-15, add row yo+16.
        const int ysub = yo - PAD;
        const int yadd = yo + PAD + 1;
        if (ysub >= 0) {
            const float* row = img + (size_t)ysub * IMG_W;
            float v0 = row[t], v1 = row[t + 256], v2 = row[t + 512], v3 = row[t + 768];
            vs0 -= v0; vq0 -= v0 * v0;
            vs1 -= v1; vq1 -= v1 * v1;
            vs2 -= v2; vq2 -= v2 * v2;
            vs3 -= v3; vq3 -= v3 * v3;
        }
        if (yadd < IMG_H) {
            const float* row = img + (size_t)yadd * IMG_W;
            float v0 = row[t], v1 = row[t + 256], v2 = row[t + 512], v3 = row[t + 768];
            vs0 += v0; vq0 += v0 * v0;
            vs1 += v1; vq1 += v1 * v1;
            vs2 += v2; vq2 += v2 * v2;
            vs3 += v3; vq3 += v3 * v3;
        }
    }
}

extern "C" void kernel_launch(void* const* d_in, const int* in_sizes, int n_in,
                              void* d_out, int out_size, void* d_ws, size_t ws_size,
                              hipStream_t stream) {
    (void)n_in; (void)out_size; (void)d_ws; (void)ws_size;
    const float* x = (const float*)d_in[0];
    float* out = (float*)d_out;
    const int B = in_sizes[0] / (IMG_H * IMG_W);           // 32
    dim3 grid(B * (IMG_H / SH));                           // 512 blocks
    lcn_fused_kernel<<<grid, 256, 0, stream>>>(x, out);
}

// Round 2
// 107.870 us; speedup vs baseline: 2.1090x; 2.1090x over previous
//
#include <hip/hip_runtime.h>
#include <math.h>

// LocalContrastNormalization: out = sigmoid(0.5*(x-mu)/(sigma+eps)),
// mu/sigma from 31x31 zero-padded box filter (separable).
// Fused single kernel:
//  - vertical box: per-thread register sliding window over rows (2 cols/thread)
//  - horizontal box: per-lane register sliding window over 16 cols, reading
//    vertical (sum,sumsq) from a TRANSPOSED LDS layout so every read is
//    base(lane) + compile-time immediate offset and lanes are consecutive
//    in LDS (2-way bank aliasing = free).
// 512 threads = 8 waves; 8 rows per phase (wave g computes row yo+g).

#define KSZ   31
#define PAD   15
#define IMG_H 1024
#define IMG_W 1024
#define SH    64                 // rows per block
#define RPP   8                  // rows per phase == waves per block
#define PHASES (SH / RPP)        // 8
#define NT    512
#define LROW  68                 // transposed LDS stride (floats)
#define LBUF  (16 * LROW)        // 1088 floats per row-buffer
#define EPSV  1e-5f

// logical column-index iv (= col + 16, covering pads) -> transposed physical
#define TPHYS(iv) (((iv) & 15) * LROW + ((iv) >> 4))

__global__ __launch_bounds__(NT, 4)
void lcn_fused_kernel(const float* __restrict__ x, float* __restrict__ out) {
    const int t     = threadIdx.x;
    const int chunk = blockIdx.x & 15;       // 16 chunks per image
    const int b     = blockIdx.x >> 4;
    const int y0    = chunk * SH;

    const float* img  = x   + (size_t)b * (IMG_H * IMG_W);
    float*       oimg = out + (size_t)b * (IMG_H * IMG_W);

    __shared__ float vsb[RPP][LBUF];   // vertical sums, transposed layout
    __shared__ float vqb[RPP][LBUF];   // vertical sum-of-squares

    // Zero-init (pads at iv 0..15 and 1040..1055 must be zero; interiors
    // are overwritten every phase). No extra barrier needed: the first
    // intra-phase barrier orders these writes before any LDS read.
    for (int i = t; i < RPP * LBUF; i += NT) {
        (&vsb[0][0])[i] = 0.f;
        (&vqb[0][0])[i] = 0.f;
    }

    // Vertical running sums for columns c0 = 2t, c0+1.
    const int c0 = 2 * t;
    float vs0 = 0.f, vq0 = 0.f, vs1 = 0.f, vq1 = 0.f;
    for (int y = y0 - PAD; y <= y0 + PAD; ++y) {   // y0+PAD <= 975 < H
        if (y < 0) continue;
        float2 v = *(const float2*)(img + (size_t)y * IMG_W + c0);
        vs0 += v.x; vq0 += v.x * v.x;
        vs1 += v.y; vq1 += v.y * v.y;
    }

    const int wave = t >> 6;         // 0..7 -> row within phase
    const int lane = t & 63;         // owns cols [16*lane, 16*lane+16)
    const int cbase = lane * 16;

    // publish addresses: iv0 = c0+16 (even) -> phys, and phys+LROW for c0+1
    const int wp = TPHYS(c0 + 16);

    const float inv = 1.0f / 961.0f;

    for (int ph = 0; ph < PHASES; ++ph) {
        const int yo = y0 + ph * RPP;

        // ---- vertical publish + slide, 8 rows ----
        #pragma unroll
        for (int r = 0; r < RPP; ++r) {
            vsb[r][wp]        = vs0;
            vsb[r][wp + LROW] = vs1;
            vqb[r][wp]        = vq0;
            vqb[r][wp + LROW] = vq1;
            const int row  = yo + r;
            const int ysub = row - PAD;
            const int yadd = row + PAD + 1;
            if (ysub >= 0) {
                float2 v = *(const float2*)(img + (size_t)ysub * IMG_W + c0);
                vs0 -= v.x; vq0 -= v.x * v.x;
                vs1 -= v.y; vq1 -= v.y * v.y;
            }
            if (yadd < IMG_H) {
                float2 v = *(const float2*)(img + (size_t)yadd * IMG_W + c0);
                vs0 += v.x; vq0 += v.x * v.x;
                vs1 += v.y; vq1 += v.y * v.y;
            }
        }
        __syncthreads();

        // ---- horizontal sliding + pointwise, wave g -> row yo+g ----
        {
            const int row = yo + wave;
            const float* vsr = &vsb[wave][lane];
            const float* vqr = &vqb[wave][lane];

            // x values for this lane's 16 output columns
            const float* xr = img + (size_t)row * IMG_W + cbase;
            float4 xa = ((const float4*)xr)[0];
            float4 xb = ((const float4*)xr)[1];
            float4 xc = ((const float4*)xr)[2];
            float4 xd = ((const float4*)xr)[3];
            float xs[16] = { xa.x, xa.y, xa.z, xa.w,  xb.x, xb.y, xb.z, xb.w,
                             xc.x, xc.y, xc.z, xc.w,  xd.x, xd.y, xd.z, xd.w };

            // warm-up: window of col cbase = logical iv cbase+1 .. cbase+31
            float hs = 0.f, hq = 0.f;
            #pragma unroll
            for (int m = 1; m <= 31; ++m) {
                const int off = ((m & 15) * LROW) + (m >> 4);  // compile-time
                hs += vsr[off];
                hq += vqr[off];
            }

            float res[16];
            #pragma unroll
            for (int j = 0; j < 16; ++j) {
                if (j > 0) {
                    const int offa = ((j - 1) * LROW) + 2;     // iv=cbase+31+j
                    const int offs = (j * LROW);               // iv=cbase+j
                    hs += vsr[offa] - vsr[offs];
                    hq += vqr[offa] - vqr[offs];
                }
                const float mean = hs * inv;
                const float var  = fmaf(-mean, mean, hq * inv);
                const float stdv = sqrtf(fmaxf(var, EPSV));
                const float norm = (xs[j] - mean) *
                                   __builtin_amdgcn_rcpf(stdv + EPSV);
                const float e    = __expf(-0.5f * norm);
                res[j] = __builtin_amdgcn_rcpf(1.0f + e);
            }

            float* orow = oimg + (size_t)row * IMG_W + cbase;
            ((float4*)orow)[0] = make_float4(res[0],  res[1],  res[2],  res[3]);
            ((float4*)orow)[1] = make_float4(res[4],  res[5],  res[6],  res[7]);
            ((float4*)orow)[2] = make_float4(res[8],  res[9],  res[10], res[11]);
            ((float4*)orow)[3] = make_float4(res[12], res[13], res[14], res[15]);
        }
        __syncthreads();   // buffers rewritten next phase
    }
}

extern "C" void kernel_launch(void* const* d_in, const int* in_sizes, int n_in,
                              void* d_out, int out_size, void* d_ws, size_t ws_size,
                              hipStream_t stream) {
    (void)n_in; (void)out_size; (void)d_ws; (void)ws_size;
    const float* x = (const float*)d_in[0];
    float* out = (float*)d_out;
    const int B = in_sizes[0] / (IMG_H * IMG_W);   // 32
    dim3 grid(B * (IMG_H / SH));                   // 512 blocks, 512 thr
    lcn_fused_kernel<<<grid, NT, 0, stream>>>(x, out);
}

// Round 3
// 92.454 us; speedup vs baseline: 2.4607x; 1.1668x over previous
//
#include <hip/hip_runtime.h>
#include <math.h>

// LocalContrastNormalization: out = sigmoid(0.5*(x-mu)/(sigma+eps)),
// mu/sigma from 31x31 zero-padded box filter (separable).
// v3: 256 threads (4 waves), SH=32 rows/block -> 1024 blocks (4 blocks/CU,
// LDS 33.8 KB). Vertical box: per-thread register sliding window, 4 cols via
// float4. Horizontal box: per-lane register sliding window over 16 cols,
// reading packed (sum,sumsq) float2 from a TRANSPOSED LDS layout so every
// read is base(lane) + compile-time immediate and lanes are consecutive.

#define KSZ   31
#define PAD   15
#define IMG_H 1024
#define IMG_W 1024
#define SH    32                 // rows per block
#define RPP   4                  // rows per phase == waves per block
#define PHASES (SH / RPP)        // 8
#define NT    256
#define LROW  66                 // transposed stride in float2 units
#define LBUF  (16 * LROW)        // 1056 float2 per row-buffer
#define EPSV  1e-5f

__global__ __launch_bounds__(NT, 4)
void lcn_fused_kernel(const float* __restrict__ x, float* __restrict__ out) {
    // XCD-aware bijective swizzle (gridDim.x % 8 == 0): consecutive work
    // chunks (same image, adjacent y) land on the same XCD -> halo re-reads
    // are L2-local.
    const int cpx = gridDim.x >> 3;
    const int bid = (blockIdx.x & 7) * cpx + (blockIdx.x >> 3);

    const int t     = threadIdx.x;
    const int chunk = bid & 31;            // 32 chunks of 32 rows per image
    const int b     = bid >> 5;
    const int y0    = chunk * SH;

    const float* img  = x   + (size_t)b * (IMG_H * IMG_W);
    float*       oimg = out + (size_t)b * (IMG_H * IMG_W);

    __shared__ float2 vbuf[RPP][LBUF];     // packed (vsum, vsumsq), transposed

    // Zero-init: pads (iv<16, iv>=1040) must be zero; interior rewritten
    // every phase. First intra-phase barrier orders these before any read.
    for (int i = t; i < RPP * LBUF; i += NT)
        (&vbuf[0][0])[i] = make_float2(0.f, 0.f);

    // Vertical running sums for columns c0..c0+3.
    const int c0 = 4 * t;
    float vs0 = 0.f, vs1 = 0.f, vs2 = 0.f, vs3 = 0.f;
    float vq0 = 0.f, vq1 = 0.f, vq2 = 0.f, vq3 = 0.f;
    for (int y = y0 - PAD; y <= y0 + PAD; ++y) {   // y0+PAD <= 1007 < H
        if (y < 0) continue;
        float4 v = *(const float4*)(img + (size_t)y * IMG_W + c0);
        vs0 += v.x; vq0 += v.x * v.x;
        vs1 += v.y; vq1 += v.y * v.y;
        vs2 += v.z; vq2 += v.z * v.z;
        vs3 += v.w; vq3 += v.w * v.w;
    }

    // Precomputed transposed publish indices for iv = c0+16+m.
    int wp0, wp1, wp2, wp3;
    {
        const int iv = c0 + 16;
        wp0 = ((iv    ) & 15) * LROW + ((iv    ) >> 4);
        wp1 = ((iv + 1) & 15) * LROW + ((iv + 1) >> 4);
        wp2 = ((iv + 2) & 15) * LROW + ((iv + 2) >> 4);
        wp3 = ((iv + 3) & 15) * LROW + ((iv + 3) >> 4);
    }

    const int wave  = t >> 6;        // 0..3 -> row within phase
    const int lane  = t & 63;        // owns cols [16*lane, 16*lane+16)
    const int cbase = lane << 4;
    const float inv = 1.0f / 961.0f;

    for (int ph = 0; ph < PHASES; ++ph) {
        const int yo = y0 + ph * RPP;

        // ---- vertical publish + slide, RPP rows ----
        #pragma unroll
        for (int r = 0; r < RPP; ++r) {
            vbuf[r][wp0] = make_float2(vs0, vq0);
            vbuf[r][wp1] = make_float2(vs1, vq1);
            vbuf[r][wp2] = make_float2(vs2, vq2);
            vbuf[r][wp3] = make_float2(vs3, vq3);
            const int row  = yo + r;
            const int ysub = row - PAD;
            const int yadd = row + PAD + 1;
            if (ysub >= 0) {
                float4 v = *(const float4*)(img + (size_t)ysub * IMG_W + c0);
                vs0 -= v.x; vq0 -= v.x * v.x;
                vs1 -= v.y; vq1 -= v.y * v.y;
                vs2 -= v.z; vq2 -= v.z * v.z;
                vs3 -= v.w; vq3 -= v.w * v.w;
            }
            if (yadd < IMG_H) {
                float4 v = *(const float4*)(img + (size_t)yadd * IMG_W + c0);
                vs0 += v.x; vq0 += v.x * v.x;
                vs1 += v.y; vq1 += v.y * v.y;
                vs2 += v.z; vq2 += v.z * v.z;
                vs3 += v.w; vq3 += v.w * v.w;
            }
        }
        __syncthreads();

        // ---- horizontal sliding + pointwise; wave g -> row yo+g ----
        {
            const int row = yo + wave;
            const float2* vr = &vbuf[wave][lane];   // lane is the >>4 dim

            // warm-up: window for col cbase = iv in [cbase+1, cbase+31]
            float hs = 0.f, hq = 0.f;
            #pragma unroll
            for (int s = 1; s <= 31; ++s) {
                const int off = (s & 15) * LROW + (s >> 4);  // compile-time
                float2 v = vr[off];
                hs += v.x; hq += v.y;
            }

            const float* xr = img + (size_t)row * IMG_W + cbase;
            float4 xa = ((const float4*)xr)[0];
            float4 xb = ((const float4*)xr)[1];
            float4 xc = ((const float4*)xr)[2];
            float4 xd = ((const float4*)xr)[3];
            float xs[16] = { xa.x, xa.y, xa.z, xa.w,  xb.x, xb.y, xb.z, xb.w,
                             xc.x, xc.y, xc.z, xc.w,  xd.x, xd.y, xd.z, xd.w };

            float res[16];
            #pragma unroll
            for (int j = 0; j < 16; ++j) {
                if (j > 0) {
                    // add iv=cbase+j+31 -> ((j-1)&15)*LROW + 2
                    // sub iv=cbase+j    -> j*LROW
                    float2 va = vr[((j - 1) & 15) * LROW + 2];
                    float2 vb = vr[j * LROW];
                    hs += va.x - vb.x;
                    hq += va.y - vb.y;
                }
                const float mean = hs * inv;
                const float var  = fmaf(-mean, mean, hq * inv);
                const float stdv = sqrtf(fmaxf(var, EPSV));
                const float norm = (xs[j] - mean) *
                                   __builtin_amdgcn_rcpf(stdv + EPSV);
                const float e    = __expf(-0.5f * norm);
                res[j] = __builtin_amdgcn_rcpf(1.0f + e);
            }

            float* orow = oimg + (size_t)row * IMG_W + cbase;
            ((float4*)orow)[0] = make_float4(res[0],  res[1],  res[2],  res[3]);
            ((float4*)orow)[1] = make_float4(res[4],  res[5],  res[6],  res[7]);
            ((float4*)orow)[2] = make_float4(res[8],  res[9],  res[10], res[11]);
            ((float4*)orow)[3] = make_float4(res[12], res[13], res[14], res[15]);
        }
        __syncthreads();   // buffers rewritten next phase
    }
}

extern "C" void kernel_launch(void* const* d_in, const int* in_sizes, int n_in,
                              void* d_out, int out_size, void* d_ws, size_t ws_size,
                              hipStream_t stream) {
    (void)n_in; (void)out_size; (void)d_ws; (void)ws_size;
    const float* x = (const float*)d_in[0];
    float* out = (float*)d_out;
    const int B = in_sizes[0] / (IMG_H * IMG_W);   // 32
    dim3 grid(B * (IMG_H / SH));                   // 1024 blocks
    lcn_fused_kernel<<<grid, NT, 0, stream>>>(x, out);
}